// Round 5
// baseline (262.481 us; speedup 1.0000x reference)
//
#include <hip/hip_runtime.h>
#include <math.h>

typedef int intx4 __attribute__((ext_vector_type(4)));
typedef int intx8 __attribute__((ext_vector_type(8)));
typedef float floatx16 __attribute__((ext_vector_type(16)));

#define N_ROWS 8192
#define KDIM 1024

// E8M0 scale bytes: 123 -> 2^-4 per side (data pre-scaled by 2^4 each side)
#define SCALE_WORD 0x7B7B7B7B

// order-preserving float->int encoding for atomicMax
__device__ __forceinline__ int fenc(float f) {
  int i = __float_as_int(f);
  return i >= 0 ? i : (i ^ 0x7fffffff);
}
__device__ __forceinline__ float fdec(int e) {
  int b = e >= 0 ? e : (e ^ 0x7fffffff);
  return __int_as_float(b);
}

// async 16B global->LDS DMA (m97 pattern: per-lane global src, LDS dest must
// equal wave-uniform base + lane*16 -- ours does by construction).
__device__ __forceinline__ void gld_lds16(const void* g, void* l) {
  __builtin_amdgcn_global_load_lds(
      (const __attribute__((address_space(1))) unsigned int*)g,
      (__attribute__((address_space(3))) unsigned int*)l, 16, 0, 0);
}

// One WAVE per row (4 rows/block, no __syncthreads): computes 1/||x|| (fp32),
// writes row normalized*16 as e4m3 via HW cvt, inits the max slot.
__global__ __launch_bounds__(256) void normalize_kernel(
    const float* __restrict__ ex, const float* __restrict__ ey,
    unsigned char* __restrict__ exn, unsigned char* __restrict__ eyn,
    int* __restrict__ rowmax, int* __restrict__ colmax) {
  const int wave = threadIdx.x >> 6, lane = threadIdx.x & 63;
  const int gr = blockIdx.x * 4 + wave;  // 0..16383
  const float* x;
  unsigned char* out;
  int* mslot;
  int row;
  if (gr < N_ROWS) {
    x = ex; out = exn; mslot = rowmax; row = gr;
  } else {
    x = ey; out = eyn; mslot = colmax; row = gr - N_ROWS;
  }
  const float4* xr = (const float4*)(x + (size_t)row * KDIM);
  float4 v[4];
  float ss = 0.f;
#pragma unroll
  for (int j = 0; j < 4; ++j) {
    v[j] = xr[lane + j * 64];  // coalesced
    ss += v[j].x * v[j].x + v[j].y * v[j].y + v[j].z * v[j].z + v[j].w * v[j].w;
  }
#pragma unroll
  for (int off = 32; off > 0; off >>= 1) ss += __shfl_xor(ss, off, 64);
  const float rs = 16.0f * rsqrtf(fmaxf(ss, 1e-24f));  // 2^4 pre-scale
  int* op = (int*)(out + (size_t)row * KDIM);
#pragma unroll
  for (int j = 0; j < 4; ++j) {
    int w = __builtin_amdgcn_cvt_pk_fp8_f32(v[j].x * rs, v[j].y * rs, 0, false);
    w = __builtin_amdgcn_cvt_pk_fp8_f32(v[j].z * rs, v[j].w * rs, w, true);
    op[lane + j * 64] = w;
  }
  if (lane == 0) mslot[row] = (int)0x80000000;  // encoded -inf floor
}

// 128x128 tile GEMM (A @ B^T, row-major K-contiguous e4m3) using MX-scaled
// mfma_scale_f32_32x32x64_f8f6f4, fused with row/col max reduction.
//
// Round-16 change: r13 structure (A direct global->reg ping-pong, B via
// DMA->LDS) at __launch_bounds__(256, 3). Cross-round ledger:
//  - r11 (A+B LDS, reg-staged writes): 119 us; LDS pipe ~62% busy =
//    binding pipe; MFMA 24%.
//  - r15 (A+B LDS, DMA writes): 121 us -- IDENTICAL. DMA removes
//    wave-issue slots but LDS-pipe write traffic remains -> null result.
//    Conclusion: must REMOVE LDS traffic, not re-issue it.
//  - r13 (A direct to regs, 1-step prefetch): 176 us, but counters prove
//    the concept never ran spill-free: (256,4) caps 128 total regs; acc=64
//    AGPR + A0/A1=32 blew the 64 arch-VGPR budget -> WRITE_SIZE 20->48 MB
//    scratch, VGPR pinned at 64, L2 round-trips inside COMPUTE.
// Fix: (256,3) -> cap 170 regs (demand ~134). Occupancy 3 blocks/CU = 12
// waves/CU ~= measured 13 at r15 -> essentially free. LDS pipe drops to
// B-only (~350 cy/block-step, below MFMA+latency); A-direct is verified
// cache-absorbed (r13: FETCH 45 MB, HBM 6%).
// Tripwires: WRITE_SIZE ~20 MB (spill), VGPR_Count ~100-130 (not 64).
//
// LDS swizzle for B (verified r8): 64-B rows, 16-B chunk c of row r at
// slot c ^ ((r>>1)&3); staging pre-swizzles the global source chunk so
// the linear lane*16 dest lands swizzle-stored; fragment reads recover
// true chunk 2h+j -> operand bytes at (half,j,b) equal global
// k = k0+(2h+j)*16+b for BOTH A and B -> exact dot-product pairing
// (absmax 0.0 through r15).
__global__ __launch_bounds__(256, 3) void gemm_max_kernel(
    const unsigned char* __restrict__ A, const unsigned char* __restrict__ B,
    int* __restrict__ rowmax, int* __restrict__ colmax) {
  constexpr int TM = 128, BK = 64, K = KDIM;
  constexpr int BUF = TM * BK;                          // 8 KB per buffer
  __shared__ __align__(16) unsigned char sB[2 * BUF];   // 16 KB (B only)

  const int bm = blockIdx.x, bn = blockIdx.y;
  const int tid = threadIdx.x;
  const int lane = tid & 63, wave = tid >> 6;
  const int wm = wave >> 1, wn = wave & 1;  // 2x2 waves of 64x64
  const int l32 = lane & 31, half = lane >> 5;
  const int fsw = (l32 >> 1) & 3;                 // f(row) = (row>>1)&3
  const int oLo = (((2 * half + 0) ^ fsw) << 4);  // swizzled slot offsets
  const int oHi = (((2 * half + 1) ^ fsw) << 4);

  const char* Bb = (const char*)(B + (size_t)bn * TM * K);

  // A direct: per-lane base at (row = bm*128 + wm*64 + l32, col = half*32).
  // Per fragment, mi adds 32 rows; per step, k0 advances 64 bytes.
  const char* gAf =
      (const char*)A + (size_t)(bm * TM + wm * 64 + l32) * K + half * 32;

  typedef union {
    intx8 v8;
    intx4 v4[2];
  } frag8;

  floatx16 acc[2][2] = {};
  frag8 A0[2], A1[2];  // ping-pong A fragment sets (32 VGPRs)

  // B staging: wave w stages rows w*32..+31 per step (2 DMAs/lane).
  // Dest (linear lane*16): row r_d = wave*32 + (lane>>2), slot lane&3.
  // Source chunk = (lane&3) ^ f(r_d); +16-row second DMA keeps same offset.
  const int src_c16 = (((lane & 3) ^ ((lane >> 3) & 3)) << 4);
  const char* gB = Bb + (size_t)(wave * 32 + (lane >> 2)) * K + src_c16;
  unsigned char* wBl = sB + wave * 2048 + lane * 16;  // linear per-lane dest

#define GLB(k0, buf)                                                  \
  do {                                                                \
    gld_lds16(gB + (size_t)(k0), wBl + (buf)*BUF);                    \
    gld_lds16(gB + (size_t)(k0) + 16 * (size_t)K, wBl + (buf)*BUF + 1024); \
  } while (0)

#define LOADA(AF, k0)                                                        \
  do {                                                                       \
    AF[0].v4[0] = *(const intx4*)(gAf + (size_t)(k0));                       \
    AF[0].v4[1] = *(const intx4*)(gAf + (size_t)(k0) + 16);                  \
    AF[1].v4[0] = *(const intx4*)(gAf + (size_t)(k0) + 32 * (size_t)K);      \
    AF[1].v4[1] = *(const intx4*)(gAf + (size_t)(k0) + 32 * (size_t)K + 16); \
  } while (0)

#define COMPUTE(cur, AF)                                                    \
  do {                                                                      \
    _Pragma("unroll") for (int ni = 0; ni < 2; ++ni) {                      \
      const unsigned char* bBase =                                          \
          &sB[(cur)*BUF + (wn * 64 + ni * 32 + l32) * BK];                  \
      frag8 bF;                                                             \
      bF.v4[0] = *(const intx4*)(bBase + oLo);                              \
      bF.v4[1] = *(const intx4*)(bBase + oHi);                              \
      _Pragma("unroll") for (int mi = 0; mi < 2; ++mi)                      \
          acc[mi][ni] = __builtin_amdgcn_mfma_scale_f32_32x32x64_f8f6f4(    \
              AF[mi].v8, bF.v8, acc[mi][ni], 0, 0, 0, SCALE_WORD, 0,        \
              SCALE_WORD);                                                  \
    }                                                                       \
  } while (0)

  // Prologue: DMA buf0, prefetch A for step 0; barrier drains vmcnt.
  GLB(0, 0);
  LOADA(A0, 0);
  __syncthreads();

  // Steady state: DMA + A-prefetch for s+1 issue BEFORE COMPUTE(s), so
  // their latency hides under the MFMA phase; the end-of-step barrier
  // (with its vmcnt drain) is the only wait. Manual 2-unroll keeps the
  // A0/A1 and buffer indices compile-time (no scratch, rule #20).
#pragma unroll 1
  for (int s = 0; s < 14; s += 2) {
    GLB((size_t)(s + 1) * BK, 1);
    LOADA(A1, (size_t)(s + 1) * BK);
    COMPUTE(0, A0);
    __syncthreads();
    GLB((size_t)(s + 2) * BK, 0);
    LOADA(A0, (size_t)(s + 2) * BK);
    COMPUTE(1, A1);
    __syncthreads();
  }
  // s = 14:
  GLB((size_t)15 * BK, 1);
  LOADA(A1, (size_t)15 * BK);
  COMPUTE(0, A0);
  __syncthreads();
  // s = 15 (epilogue, no prefetch):
  COMPUTE(1, A1);

#undef GLB
#undef LOADA
#undef COMPUTE

  // 32x32 C/D layout (m74/m101, dtype-independent):
  //   col = lane&31, row = (reg&3) + 8*(reg>>2) + 4*(lane>>5), reg in [0,16)
  // Row maxes: in-lane over ni, shuffle across 32 cols (masks 1..16 stay
  // within a half), l32==0 lanes write.
#pragma unroll
  for (int mi = 0; mi < 2; ++mi) {
#pragma unroll
    for (int reg = 0; reg < 16; ++reg) {
      float v = fmaxf(acc[mi][0][reg], acc[mi][1][reg]);
#pragma unroll
      for (int m = 1; m < 32; m <<= 1) v = fmaxf(v, __shfl_xor(v, m, 64));
      if (l32 == 0) {
        const int grow = bm * TM + wm * 64 + mi * 32 +
                         (reg & 3) + 8 * (reg >> 2) + 4 * half;
        atomicMax(&rowmax[grow], fenc(v));
      }
    }
  }
  // Col maxes: in-lane over mi,reg (32 vals), combine halves via xor 32.
#pragma unroll
  for (int ni = 0; ni < 2; ++ni) {
    float v = -3.402823466e38f;
#pragma unroll
    for (int mi = 0; mi < 2; ++mi)
#pragma unroll
      for (int reg = 0; reg < 16; ++reg) v = fmaxf(v, acc[mi][ni][reg]);
    v = fmaxf(v, __shfl_xor(v, 32, 64));
    if (half == 0) {
      const int gcol = bn * TM + wn * 64 + ni * 32 + l32;
      atomicMax(&colmax[gcol], fenc(v));
    }
  }
}

__global__ __launch_bounds__(1024) void finalize_kernel(
    const int* __restrict__ rowmax, const int* __restrict__ colmax,
    float* __restrict__ out) {
  const int tid = threadIdx.x;
  float s1 = 0.f, s2 = 0.f;
  for (int i = tid; i < N_ROWS; i += 1024) {
    s1 += 1.0f - fdec(rowmax[i]);
    s2 += 1.0f - fdec(colmax[i]);
  }
#pragma unroll
  for (int off = 32; off > 0; off >>= 1) {
    s1 += __shfl_down(s1, off, 64);
    s2 += __shfl_down(s2, off, 64);
  }
  __shared__ float r1[16], r2[16];
  if ((tid & 63) == 0) {
    r1[tid >> 6] = s1;
    r2[tid >> 6] = s2;
  }
  __syncthreads();
  if (tid == 0) {
    const double SIGMA = 0.3;
    const double H_CONST = 0.5 * log(2.0 * 3.14159265358979323846 * SIGMA * SIGMA) + 0.5;
    const float HS = (float)(H_CONST / SIGMA);
    float a1 = 0.f, a2 = 0.f;
#pragma unroll
    for (int w = 0; w < 16; ++w) {
      a1 += r1[w];
      a2 += r2[w];
    }
    out[0] = HS * a1;
    out[1] = HS * a2;
  }
}

extern "C" void kernel_launch(void* const* d_in, const int* in_sizes, int n_in,
                              void* d_out, int out_size, void* d_ws, size_t ws_size,
                              hipStream_t stream) {
  const float* ex = (const float*)d_in[0];
  const float* ey = (const float*)d_in[1];
  float* out = (float*)d_out;
  char* ws = (char*)d_ws;

  unsigned char* exn = (unsigned char*)ws;                                   // 8 MB
  unsigned char* eyn = (unsigned char*)(ws + (size_t)N_ROWS * KDIM);         // 8 MB
  int* rowmax = (int*)(ws + (size_t)N_ROWS * KDIM * 2);                      // 32 KB
  int* colmax = rowmax + N_ROWS;                                             // 32 KB

  normalize_kernel<<<2 * N_ROWS / 4, 256, 0, stream>>>(ex, ey, exn, eyn, rowmax, colmax);
  gemm_max_kernel<<<dim3(64, 64), 256, 0, stream>>>(exn, eyn, rowmax, colmax);
  finalize_kernel<<<1, 1024, 0, stream>>>(rowmax, colmax, out);
}

// Round 6
// 202.894 us; speedup vs baseline: 1.2937x; 1.2937x over previous
//
#include <hip/hip_runtime.h>
#include <math.h>

typedef int intx4 __attribute__((ext_vector_type(4)));
typedef int intx8 __attribute__((ext_vector_type(8)));
typedef float floatx16 __attribute__((ext_vector_type(16)));

#define N_ROWS 8192
#define KDIM 1024

// E8M0 scale bytes: 123 -> 2^-4 per side (data pre-scaled by 2^4 each side)
#define SCALE_WORD 0x7B7B7B7B

// order-preserving float->int encoding for atomicMax
__device__ __forceinline__ int fenc(float f) {
  int i = __float_as_int(f);
  return i >= 0 ? i : (i ^ 0x7fffffff);
}
__device__ __forceinline__ float fdec(int e) {
  int b = e >= 0 ? e : (e ^ 0x7fffffff);
  return __int_as_float(b);
}

// async 16B global->LDS DMA (m97 pattern: per-lane global src, LDS dest must
// equal wave-uniform base + lane*16 -- ours does by construction).
__device__ __forceinline__ void gld_lds16(const void* g, void* l) {
  __builtin_amdgcn_global_load_lds(
      (const __attribute__((address_space(1))) unsigned int*)g,
      (__attribute__((address_space(3))) unsigned int*)l, 16, 0, 0);
}

// One WAVE per row (4 rows/block, no __syncthreads): computes 1/||x|| (fp32),
// writes row normalized*16 as e4m3 via HW cvt, inits the max slot.
__global__ __launch_bounds__(256) void normalize_kernel(
    const float* __restrict__ ex, const float* __restrict__ ey,
    unsigned char* __restrict__ exn, unsigned char* __restrict__ eyn,
    int* __restrict__ rowmax, int* __restrict__ colmax) {
  const int wave = threadIdx.x >> 6, lane = threadIdx.x & 63;
  const int gr = blockIdx.x * 4 + wave;  // 0..16383
  const float* x;
  unsigned char* out;
  int* mslot;
  int row;
  if (gr < N_ROWS) {
    x = ex; out = exn; mslot = rowmax; row = gr;
  } else {
    x = ey; out = eyn; mslot = colmax; row = gr - N_ROWS;
  }
  const float4* xr = (const float4*)(x + (size_t)row * KDIM);
  float4 v[4];
  float ss = 0.f;
#pragma unroll
  for (int j = 0; j < 4; ++j) {
    v[j] = xr[lane + j * 64];  // coalesced
    ss += v[j].x * v[j].x + v[j].y * v[j].y + v[j].z * v[j].z + v[j].w * v[j].w;
  }
#pragma unroll
  for (int off = 32; off > 0; off >>= 1) ss += __shfl_xor(ss, off, 64);
  const float rs = 16.0f * rsqrtf(fmaxf(ss, 1e-24f));  // 2^4 pre-scale
  int* op = (int*)(out + (size_t)row * KDIM);
#pragma unroll
  for (int j = 0; j < 4; ++j) {
    int w = __builtin_amdgcn_cvt_pk_fp8_f32(v[j].x * rs, v[j].y * rs, 0, false);
    w = __builtin_amdgcn_cvt_pk_fp8_f32(v[j].z * rs, v[j].w * rs, w, true);
    op[lane + j * 64] = w;
  }
  if (lane == 0) mslot[row] = (int)0x80000000;  // encoded -inf floor
}

// 128x128 tile GEMM (A @ B^T, row-major K-contiguous e4m3) using MX-scaled
// mfma_scale_f32_32x32x64_f8f6f4, fused with row/col max reduction.
//
// Round-17 change: counted-vmcnt pipeline (T3+T4), r15 body. Ledger:
//   r11 (A+B LDS, reg-staged)  119 us  MfmaUtil 25
//   r15 (A+B LDS, DMA-staged)  121 us  MfmaUtil 23   (write removal: null)
//   r13/r14/r16 (A-direct)     176-178 us, 15.8      (spill-free == spilled)
// => bottleneck is NOT LDS throughput; it's the per-step vmcnt(0)+barrier
// drain (__syncthreads semantics force a full VMEM drain each step; m233's
// 2-phase stall regime). Fix = the m201 mechanism: raw s_barrier + counted
// s_waitcnt vmcnt(4), staging 2 tiles deep so 8 DMAs/wave stay in flight
// and NO full drain occurs in the loop:
//   STAGE(t0,b0); STAGE(t1,b1);
//   loop: vmcnt(4); bar; COMPUTE(cur); bar; STAGE(t+2, buf[cur]);
// Hazards: per-wave vmem queue holds exactly the 8 STAGE DMAs (no other
// in-loop vmem; atomics are post-loop); in-order retirement (m135) means
// vmcnt(4) == "oldest tile's 4 DMAs done"; own-wave vmcnt BEFORE barrier-1
// => after barrier-1 every wave's tile-s DMAs are complete (cross-wave
// visibility); barrier-2 orders all readers before the buffer overwrite.
// sched_barrier(0) after each waitcnt (rule #18 guard).
// COMPUTE and byte placement identical to r15 -> absmax 0.0 preserved.
// Tripwires: absmax != 0 or hang => barrier analysis wrong, revert.
//
// LDS swizzle (verified r8): 64-B rows, 16-B chunk c of row r at slot
// c ^ ((r>>1)&3); staging pre-swizzles the global source chunk so the
// linear lane*16 dest lands swizzle-stored; fragment reads recover true
// chunk 2h+j -> operand bytes at (half,j,b) equal global k=k0+(2h+j)*16+b
// for BOTH A and B -> exact dot-product pairing (absmax 0.0 thru r16).
__global__ __launch_bounds__(256, 4) void gemm_max_kernel(
    const unsigned char* __restrict__ A, const unsigned char* __restrict__ B,
    int* __restrict__ rowmax, int* __restrict__ colmax) {
  constexpr int TM = 128, BK = 64, K = KDIM;
  constexpr int BUF = TM * BK;                          // 8 KB per buffer
  __shared__ __align__(16) unsigned char sA[2 * BUF];   // 16 KB
  __shared__ __align__(16) unsigned char sB[2 * BUF];   // 16 KB

  const int bm = blockIdx.x, bn = blockIdx.y;
  const int tid = threadIdx.x;
  const int lane = tid & 63, wave = tid >> 6;
  const int wm = wave >> 1, wn = wave & 1;  // 2x2 waves of 64x64
  const int l32 = lane & 31, half = lane >> 5;
  const int fsw = (l32 >> 1) & 3;                 // f(row) = (row>>1)&3
  const int oLo = (((2 * half + 0) ^ fsw) << 4);  // swizzled slot offsets
  const int oHi = (((2 * half + 1) ^ fsw) << 4);

  const char* Ab = (const char*)(A + (size_t)bm * TM * K);
  const char* Bb = (const char*)(B + (size_t)bn * TM * K);

  floatx16 acc[2][2] = {};

  // Staging: wave w stages rows w*32..+31 of each tile per step (2 DMAs
  // per array per lane). Dest (linear lane*16): row r_d = wave*32 +
  // (lane>>2), slot lane&3. Source chunk = (lane&3) ^ f(r_d); the +16-row
  // second DMA keeps the same offset (f(r+16)==f(r)).
  const int src_c16 = (((lane & 3) ^ ((lane >> 3) & 3)) << 4);
  const char* gA = Ab + (size_t)(wave * 32 + (lane >> 2)) * K + src_c16;
  const char* gB = Bb + (size_t)(wave * 32 + (lane >> 2)) * K + src_c16;
  unsigned char* wA = sA + wave * 2048 + lane * 16;  // linear per-lane dest
  unsigned char* wB = sB + wave * 2048 + lane * 16;

  // 4 DMAs per STAGE per lane -> per-wave vmem queue = 4 per tile.
#define STAGE(k0, buf)                                                     \
  do {                                                                     \
    gld_lds16(gA + (size_t)(k0), wA + (buf)*BUF);                          \
    gld_lds16(gA + (size_t)(k0) + 16 * (size_t)K, wA + (buf)*BUF + 1024);  \
    gld_lds16(gB + (size_t)(k0), wB + (buf)*BUF);                          \
    gld_lds16(gB + (size_t)(k0) + 16 * (size_t)K, wB + (buf)*BUF + 1024);  \
  } while (0)

  // counted wait: retire down to N outstanding (never 0 in the loop).
#define WAITV(N)                                          \
  do {                                                    \
    asm volatile("s_waitcnt vmcnt(" #N ")" ::: "memory"); \
    __builtin_amdgcn_sched_barrier(0);                    \
  } while (0)

#define COMPUTE(cur)                                                        \
  do {                                                                      \
    intx8 aF[2];                                                            \
    _Pragma("unroll") for (int mi = 0; mi < 2; ++mi) {                      \
      const unsigned char* aBase =                                          \
          &sA[(cur)*BUF + (wm * 64 + mi * 32 + l32) * BK];                  \
      const intx4 lo = *(const intx4*)(aBase + oLo);                        \
      const intx4 hi = *(const intx4*)(aBase + oHi);                        \
      aF[mi] = __builtin_shufflevector(lo, hi, 0, 1, 2, 3, 4, 5, 6, 7);     \
    }                                                                       \
    _Pragma("unroll") for (int ni = 0; ni < 2; ++ni) {                      \
      const unsigned char* bBase =                                          \
          &sB[(cur)*BUF + (wn * 64 + ni * 32 + l32) * BK];                  \
      const intx4 lo = *(const intx4*)(bBase + oLo);                        \
      const intx4 hi = *(const intx4*)(bBase + oHi);                        \
      const intx8 bF =                                                      \
          __builtin_shufflevector(lo, hi, 0, 1, 2, 3, 4, 5, 6, 7);          \
      _Pragma("unroll") for (int mi = 0; mi < 2; ++mi)                      \
          acc[mi][ni] = __builtin_amdgcn_mfma_scale_f32_32x32x64_f8f6f4(    \
              aF[mi], bF, acc[mi][ni], 0, 0, 0, SCALE_WORD, 0,              \
              SCALE_WORD);                                                  \
    }                                                                       \
  } while (0)

  // Prologue: 2 tiles in flight (8 DMAs).
  STAGE(0, 0);
  STAGE(BK, 1);

  // Steady state: vmcnt(4) retires exactly the current tile's 4 DMAs;
  // barrier-1 makes them cross-wave visible; barrier-2 protects the
  // buffer overwrite. The 4 DMAs for tile s+2 stay in flight across both
  // barriers of the next step (no full drain anywhere in the loop).
#pragma unroll 1
  for (int s = 0; s < 14; s += 2) {
    WAITV(4);
    __builtin_amdgcn_s_barrier();
    COMPUTE(0);
    __builtin_amdgcn_s_barrier();
    STAGE((size_t)(s + 2) * BK, 0);
    WAITV(4);
    __builtin_amdgcn_s_barrier();
    COMPUTE(1);
    __builtin_amdgcn_s_barrier();
    STAGE((size_t)(s + 3) * BK, 1);
  }
  // s = 14 (tile 14 in buf0; tile 15 still in flight):
  WAITV(4);
  __builtin_amdgcn_s_barrier();
  COMPUTE(0);
  // s = 15 (final drain is outside the steady loop):
  WAITV(0);
  __builtin_amdgcn_s_barrier();
  COMPUTE(1);

#undef STAGE
#undef WAITV
#undef COMPUTE

  // 32x32 C/D layout (m74/m101, dtype-independent):
  //   col = lane&31, row = (reg&3) + 8*(reg>>2) + 4*(lane>>5), reg in [0,16)
  // Row maxes: in-lane over ni, shuffle across 32 cols (masks 1..16 stay
  // within a half), l32==0 lanes write.
#pragma unroll
  for (int mi = 0; mi < 2; ++mi) {
#pragma unroll
    for (int reg = 0; reg < 16; ++reg) {
      float v = fmaxf(acc[mi][0][reg], acc[mi][1][reg]);
#pragma unroll
      for (int m = 1; m < 32; m <<= 1) v = fmaxf(v, __shfl_xor(v, m, 64));
      if (l32 == 0) {
        const int grow = bm * TM + wm * 64 + mi * 32 +
                         (reg & 3) + 8 * (reg >> 2) + 4 * half;
        atomicMax(&rowmax[grow], fenc(v));
      }
    }
  }
  // Col maxes: in-lane over mi,reg (32 vals), combine halves via xor 32.
#pragma unroll
  for (int ni = 0; ni < 2; ++ni) {
    float v = -3.402823466e38f;
#pragma unroll
    for (int mi = 0; mi < 2; ++mi)
#pragma unroll
      for (int reg = 0; reg < 16; ++reg) v = fmaxf(v, acc[mi][ni][reg]);
    v = fmaxf(v, __shfl_xor(v, 32, 64));
    if (half == 0) {
      const int gcol = bn * TM + wn * 64 + ni * 32 + l32;
      atomicMax(&colmax[gcol], fenc(v));
    }
  }
}

__global__ __launch_bounds__(1024) void finalize_kernel(
    const int* __restrict__ rowmax, const int* __restrict__ colmax,
    float* __restrict__ out) {
  const int tid = threadIdx.x;
  float s1 = 0.f, s2 = 0.f;
  for (int i = tid; i < N_ROWS; i += 1024) {
    s1 += 1.0f - fdec(rowmax[i]);
    s2 += 1.0f - fdec(colmax[i]);
  }
#pragma unroll
  for (int off = 32; off > 0; off >>= 1) {
    s1 += __shfl_down(s1, off, 64);
    s2 += __shfl_down(s2, off, 64);
  }
  __shared__ float r1[16], r2[16];
  if ((tid & 63) == 0) {
    r1[tid >> 6] = s1;
    r2[tid >> 6] = s2;
  }
  __syncthreads();
  if (tid == 0) {
    const double SIGMA = 0.3;
    const double H_CONST = 0.5 * log(2.0 * 3.14159265358979323846 * SIGMA * SIGMA) + 0.5;
    const float HS = (float)(H_CONST / SIGMA);
    float a1 = 0.f, a2 = 0.f;
#pragma unroll
    for (int w = 0; w < 16; ++w) {
      a1 += r1[w];
      a2 += r2[w];
    }
    out[0] = HS * a1;
    out[1] = HS * a2;
  }
}

extern "C" void kernel_launch(void* const* d_in, const int* in_sizes, int n_in,
                              void* d_out, int out_size, void* d_ws, size_t ws_size,
                              hipStream_t stream) {
  const float* ex = (const float*)d_in[0];
  const float* ey = (const float*)d_in[1];
  float* out = (float*)d_out;
  char* ws = (char*)d_ws;

  unsigned char* exn = (unsigned char*)ws;                                   // 8 MB
  unsigned char* eyn = (unsigned char*)(ws + (size_t)N_ROWS * KDIM);         // 8 MB
  int* rowmax = (int*)(ws + (size_t)N_ROWS * KDIM * 2);                      // 32 KB
  int* colmax = rowmax + N_ROWS;                                             // 32 KB

  normalize_kernel<<<2 * N_ROWS / 4, 256, 0, stream>>>(ex, ey, exn, eyn, rowmax, colmax);
  gemm_max_kernel<<<dim3(64, 64), 256, 0, stream>>>(exn, eyn, rowmax, colmax);
  finalize_kernel<<<1, 1024, 0, stream>>>(rowmax, colmax, out);
}